// Round 9
// baseline (184.001 us; speedup 1.0000x reference)
//
#include <hip/hip_runtime.h>

#define KDIM 1024

typedef __attribute__((ext_vector_type(8))) short bf16x8;
typedef __attribute__((ext_vector_type(4))) short short4v;
typedef __attribute__((ext_vector_type(4))) float f32x4;
typedef __attribute__((ext_vector_type(2))) unsigned uint2v;

__device__ __forceinline__ short f2bf(float f) {
    union { float f; unsigned u; } x; x.f = f;
    unsigned r = x.u + 0x7fffu + ((x.u >> 16) & 1u);   // RNE
    return (short)(r >> 16);
}

__device__ __forceinline__ bf16x8 cvt8(f32x4 a, f32x4 b) {
    union { unsigned u[4]; bf16x8 v; } r;
    asm("v_cvt_pk_bf16_f32 %0, %1, %2" : "=v"(r.u[0]) : "v"(a.x), "v"(a.y));
    asm("v_cvt_pk_bf16_f32 %0, %1, %2" : "=v"(r.u[1]) : "v"(a.z), "v"(a.w));
    asm("v_cvt_pk_bf16_f32 %0, %1, %2" : "=v"(r.u[2]) : "v"(b.x), "v"(b.y));
    asm("v_cvt_pk_bf16_f32 %0, %1, %2" : "=v"(r.u[3]) : "v"(b.z), "v"(b.w));
    return r.v;
}

__device__ __forceinline__ void gload16(const void* g, void* l) {
    __builtin_amdgcn_global_load_lds(
        (const __attribute__((address_space(1))) void*)g,
        (__attribute__((address_space(3))) void*)l, 16, 0, 0);
}

#define WAIT_VM(n)  asm volatile("s_waitcnt vmcnt(" #n ")" ::: "memory")
#define BARSYNC() do { asm volatile("s_waitcnt lgkmcnt(0)" ::: "memory"); \
                       __builtin_amdgcn_s_barrier();                      \
                       asm volatile("" ::: "memory"); } while (0)
#define BARRIER() do { asm volatile("" ::: "memory"); \
                       __builtin_amdgcn_s_barrier();  \
                       asm volatile("" ::: "memory"); } while (0)

// ---------------------------------------------------------------------------
// Decoder GEMM v5 — producer/consumer wave specialization.
// C[m][n] = sum_k A[m][k]*W[n][k] + bias[n]; M=256, K=1024, N=50000.
// 782 blocks x 512 thr (8 waves), 1 block/CU (LDS 128 KB). Panel = 64 W rows,
// processed in 2 phases of 32 rows; Wlds ring = 2 x [32 rows][2 KB bf16].
//
// Waves 0-3 (PRODUCERS): stream W fully sequentially -- each wave owns a
// contiguous run of rows (8 rows x 4 KB = 32 KB monotone per phase), plain
// f32x4 loads (lane i -> byte i*16: one instr = 1 KB contiguous), 2-row
// software pipeline, cvt_pk->bf16, XOR-swizzled ds_write. Their vmcnt stream
// contains ONLY W loads -> never drained by compute waits (the R3-R8 wall).
//
// Waves 4-7 (CONSUMERS): per phase compute C[256 x 32 cols] over full K.
// Wave cw owns 64 A-rows: per kf 4 A-frag global loads (L2-resident x_frag,
// own per-wave vmcnt), 2 swizzled B ds_reads, 8 MFMA. acc[4][2].
// One barrier per phase handoff. Consumers are ~2x faster than the stream,
// so HBM stays saturated; compute rides along.
// ---------------------------------------------------------------------------
__launch_bounds__(512, 1)
__global__ void gemm_dec5(const short* __restrict__ A, const float* __restrict__ W,
                          float* __restrict__ C, const float* __restrict__ bias, int N)
{
    __shared__ __align__(1024) char lds[2][65536];   // [buf][32 rows][2048 B]

    const int n0 = blockIdx.x * 64;
    const int t = threadIdx.x;
    const int lane = t & 63;
    const int w = t >> 6;        // 0..7
    const int cl = lane & 15;
    const int kc = lane >> 4;    // 0..3

    // swizzled ds_write of one fp32 row-quarter (as bf16 8B granule):
    // quarter q chunk c = q*32 + (lane>>1); store at chunk (c ^ (r&7)).
    auto wstore = [&](char* base, int r, int q, f32x4 v) {
        unsigned lo, hi;
        asm("v_cvt_pk_bf16_f32 %0, %1, %2" : "=v"(lo) : "v"(v.x), "v"(v.y));
        asm("v_cvt_pk_bf16_f32 %0, %1, %2" : "=v"(hi) : "v"(v.z), "v"(v.w));
        int c = q * 32 + (lane >> 1);
        int addr = r * 2048 + (((c ^ (r & 7))) << 4) + ((lane & 1) << 3);
        uint2v d; d.x = lo; d.y = hi;
        *(uint2v*)(base + addr) = d;
    };

    // stream local rows [r0, r0+NR) of phase ph into buf: per row 4 KB read as
    // 4 contiguous 1-KB wave loads; 2-row software pipeline (8 f32x4 live).
    auto stream_rows = [&](int ph, int buf, int r0, int nr) {
        char* base = lds[buf];
        int rowg = n0 + ph * 32 + r0;
        rowg = rowg < N ? rowg : N - 1;
        const float* src = W + (size_t)rowg * KDIM + lane * 4;
        f32x4 c0 = *(const f32x4*)(src);
        f32x4 c1 = *(const f32x4*)(src + 256);
        f32x4 c2 = *(const f32x4*)(src + 512);
        f32x4 c3 = *(const f32x4*)(src + 768);
        for (int r = r0; r < r0 + nr; ++r) {
            f32x4 d0, d1, d2, d3;
            if (r + 1 < r0 + nr) {
                int rg = n0 + ph * 32 + r + 1;
                rg = rg < N ? rg : N - 1;
                const float* s2 = W + (size_t)rg * KDIM + lane * 4;
                d0 = *(const f32x4*)(s2);
                d1 = *(const f32x4*)(s2 + 256);
                d2 = *(const f32x4*)(s2 + 512);
                d3 = *(const f32x4*)(s2 + 768);
            }
            wstore(base, r, 0, c0);
            wstore(base, r, 1, c1);
            wstore(base, r, 2, c2);
            wstore(base, r, 3, c3);
            c0 = d0; c1 = d1; c2 = d2; c3 = d3;
        }
    };

    // consumer: compute phase ph from buf. Wave cw = w-4 owns A rows
    // [cw*64, cw*64+64): mf 0..3; cols = 32 of this phase: nf 0..1.
    auto consume = [&](int ph, int buf) {
        const char* base = lds[buf];
        const int cw = w - 4;
        f32x4 acc[4][2];
        #pragma unroll
        for (int i = 0; i < 4; ++i) {
            acc[i][0] = (f32x4){0.f, 0.f, 0.f, 0.f};
            acc[i][1] = (f32x4){0.f, 0.f, 0.f, 0.f};
        }
        #pragma unroll
        for (int kf = 0; kf < 32; ++kf) {
            bf16x8 a[4], b[2];
            #pragma unroll
            for (int mf = 0; mf < 4; ++mf)
                a[mf] = *(const bf16x8*)(A + (size_t)(((cw * 4 + mf) * 32 + kf) * 64 + lane) * 8);
            #pragma unroll
            for (int nf = 0; nf < 2; ++nf) {
                int row = nf * 16 + cl;
                b[nf] = *(const bf16x8*)(base + row * 2048 + (((kf * 4 + kc) ^ (row & 7)) << 4));
            }
            #pragma unroll
            for (int mf = 0; mf < 4; ++mf) {
                acc[mf][0] = __builtin_amdgcn_mfma_f32_16x16x32_bf16(a[mf], b[0], acc[mf][0], 0, 0, 0);
                acc[mf][1] = __builtin_amdgcn_mfma_f32_16x16x32_bf16(a[mf], b[1], acc[mf][1], 0, 0, 0);
            }
        }
        // epilogue: col = lane&15, row = (lane>>4)*4 + reg
        #pragma unroll
        for (int mf = 0; mf < 4; ++mf) {
            int row = cw * 64 + mf * 16 + kc * 4;
            #pragma unroll
            for (int nf = 0; nf < 2; ++nf) {
                int col = n0 + ph * 32 + nf * 16 + cl;
                if (col < N) {
                    float bv = bias[col];
                    #pragma unroll
                    for (int r = 0; r < 4; ++r)
                        C[(size_t)(row + r) * N + col] = acc[mf][nf][r] + bv;
                }
            }
        }
    };

    // prologue: ALL 8 waves stream phase 0 (4 rows each)
    stream_rows(0, 0, w * 4, 4);
    BARSYNC();

    if (w < 4) {
        stream_rows(1, 1, w * 8, 8);     // producers: stream phase 1
    } else {
        consume(0, 0);                   // consumers: compute phase 0
    }
    BARSYNC();

    if (w >= 4) consume(1, 1);           // compute phase 1
}

// ---------------------------------------------------------------------------
// GRU gemm (R3 structure, proven; weights L3-resident).
// ---------------------------------------------------------------------------
template<int NF, bool PRED>
__launch_bounds__(256, 2)
__global__ void gemm_pipe(const short* __restrict__ A0, const float* __restrict__ W0,
                          float* __restrict__ C0, int nb0,
                          const short* __restrict__ A1, const float* __restrict__ W1,
                          float* __restrict__ C1,
                          const float* __restrict__ bias, int N, int ldc)
{
    constexpr int WBYTES = NF * 4096;
    constexpr int BUFB   = 16384 + WBYTES;
    __shared__ __align__(1024) char lds[3 * BUFB];

    const int bx = blockIdx.x;
    const short* A; const float* W; float* C; int n0;
    if (bx < nb0) { A = A0; W = W0; C = C0; n0 = bx * (32 * NF); }
    else          { A = A1; W = W1; C = C1; n0 = (bx - nb0) * (32 * NF); }

    const int t = threadIdx.x;
    const int lane = t & 63;
    const int w = t >> 6;
    const int wr = w >> 1;
    const int wc = w & 1;

    const float* gW[NF];
    #pragma unroll
    for (int i = 0; i < NF; ++i) {
        int sl = (i * 4 + w) * 64 + lane;
        int row = sl >> 3, cc = sl & 7;
        int rowg = n0 + row;
        if (PRED) rowg = (rowg < N) ? rowg : (N - 1);
        gW[i] = W + (size_t)rowg * KDIM + ((cc ^ (row & 7)) << 2);
    }
    const short* gA[4];
    #pragma unroll
    for (int j = 0; j < 4; ++j)
        gA[j] = A + (size_t)(j * 4 + w) * 16384 + lane * 8;

    f32x4 acc[8][NF];
    #pragma unroll
    for (int i = 0; i < 8; ++i)
        #pragma unroll
        for (int j = 0; j < NF; ++j)
            acc[i][j] = (f32x4){0.f, 0.f, 0.f, 0.f};

    auto stage = [&](int s, int buf) {
        char* base = lds + buf * BUFB;
        #pragma unroll
        for (int i = 0; i < NF; ++i)
            gload16(gW[i] + s * 32, base + 16384 + (i * 4 + w) * 1024);
        #pragma unroll
        for (int j = 0; j < 4; ++j)
            gload16(gA[j] + s * 512, base + (j * 4 + w) * 1024);
    };

    auto compute = [&](int buf) {
        const char* base = lds + buf * BUFB;
        const char* Wb = base + 16384;
        bf16x8 bfr[NF];
        #pragma unroll
        for (int nf = 0; nf < NF; ++nf) {
            int row = (wc * NF + nf) * 16 + (lane & 15);
            int c0 = (lane >> 4) << 1;
            f32x4 lo = *(const f32x4*)(Wb + row * 128 + ((c0 ^ (row & 7)) << 4));
            f32x4 hi = *(const f32x4*)(Wb + row * 128 + (((c0 + 1) ^ (row & 7)) << 4));
            bfr[nf] = cvt8(lo, hi);
        }
        #pragma unroll
        for (int mf = 0; mf < 8; ++mf) {
            bf16x8 a = *(const bf16x8*)(base + (wr * 8 + mf) * 1024 + lane * 16);
            #pragma unroll
            for (int nf = 0; nf < NF; ++nf)
                acc[mf][nf] = __builtin_amdgcn_mfma_f32_16x16x32_bf16(a, bfr[nf], acc[mf][nf], 0, 0, 0);
        }
    };

    stage(0, 0);
    stage(1, 1);

    int bc = 0, bp = 2;
    for (int s = 0; s < 32; ++s) {
        if (s + 2 < 32) {
            stage(s + 2, bp);
            if constexpr (NF == 2) WAIT_VM(12); else WAIT_VM(10);
        } else if (s + 2 == 32) {
            if constexpr (NF == 2) WAIT_VM(6); else WAIT_VM(5);
        } else {
            WAIT_VM(0);
        }
        BARRIER();
        compute(bc);
        BARRIER();
        bc = (bc == 2) ? 0 : bc + 1;
        bp = (bp == 2) ? 0 : bp + 1;
    }

    #pragma unroll
    for (int mf = 0; mf < 8; ++mf) {
        int row = wr * 128 + mf * 16 + ((lane >> 4) << 2);
        #pragma unroll
        for (int nf = 0; nf < NF; ++nf) {
            int col = n0 + (wc * NF + nf) * 16 + (lane & 15);
            if (PRED && col >= N) continue;
            float bvv = bias ? bias[col] : 0.0f;
            #pragma unroll
            for (int r = 0; r < 4; ++r)
                C[(size_t)(row + r) * ldc + col] = acc[mf][nf][r] + bvv;
        }
    }
}

// Gather embedding row / convert hidden rows into bf16 fragment layout.
__global__ void prep_kernel(const int* __restrict__ ids, const float* __restrict__ hidden,
                            const float* __restrict__ emb,
                            short* __restrict__ x_frag, short* __restrict__ h_frag)
{
    const int m = blockIdx.x;
    const int which = blockIdx.y;
    const int j = threadIdx.x << 3;

    const float* src;
    short* dst;
    if (which == 0) { src = emb + (size_t)ids[m] * KDIM; dst = x_frag; }
    else {
        src = hidden + ((size_t)(which - 1) * 256 + m) * KDIM;
        dst = h_frag + (size_t)(which - 1) * 256 * KDIM;
    }
    f32x4 v0 = *(const f32x4*)(src + j);
    f32x4 v1 = *(const f32x4*)(src + j + 4);
    int mf = m >> 4, rr = m & 15, kf = j >> 5, g = (j >> 3) & 3;
    short* p = dst + (size_t)((mf * 32 + kf) * 64 + g * 16 + rr) * 8;
    short4v a, b;
    a.x = f2bf(v0.x); a.y = f2bf(v0.y); a.z = f2bf(v0.z); a.w = f2bf(v0.w);
    b.x = f2bf(v1.x); b.y = f2bf(v1.y); b.z = f2bf(v1.z); b.w = f2bf(v1.w);
    *(short4v*)p = a;
    *(short4v*)(p + 4) = b;
}

// GRU gates: h_new = (1-z)*n + z*h ; writes fp32 hidden_out and bf16 x fragments.
__global__ void gate_kernel(const float* __restrict__ gi, const float* __restrict__ gh,
                            const float* __restrict__ bi, const float* __restrict__ bh,
                            const float* __restrict__ hprev, float* __restrict__ hout,
                            short* __restrict__ x_frag)
{
    const int m = blockIdx.x;
    const int j = threadIdx.x << 3;
    const float* gim = gi + (size_t)m * 3072;
    const float* ghm = gh + (size_t)m * 3072;
    const float* hp = hprev + (size_t)m * KDIM;
    float* ho = hout + (size_t)m * KDIM;
    int mf = m >> 4, rr = m & 15, kf = j >> 5, g = (j >> 3) & 3;
    short* xp = x_frag + (size_t)((mf * 32 + kf) * 64 + g * 16 + rr) * 8;

    #pragma unroll
    for (int half = 0; half < 2; ++half) {
        int jj = j + half * 4;
        f32x4 vir = *(const f32x4*)(gim + jj);
        f32x4 viz = *(const f32x4*)(gim + 1024 + jj);
        f32x4 vin = *(const f32x4*)(gim + 2048 + jj);
        f32x4 vhr = *(const f32x4*)(ghm + jj);
        f32x4 vhz = *(const f32x4*)(ghm + 1024 + jj);
        f32x4 vhn = *(const f32x4*)(ghm + 2048 + jj);
        f32x4 bir = *(const f32x4*)(bi + jj);
        f32x4 biz = *(const f32x4*)(bi + 1024 + jj);
        f32x4 bin = *(const f32x4*)(bi + 2048 + jj);
        f32x4 bhr = *(const f32x4*)(bh + jj);
        f32x4 bhz = *(const f32x4*)(bh + 1024 + jj);
        f32x4 bhn = *(const f32x4*)(bh + 2048 + jj);
        f32x4 vh  = *(const f32x4*)(hp + jj);
        f32x4 outv;
        short4v xb;
        #pragma unroll
        for (int e = 0; e < 4; ++e) {
            float r = 1.f / (1.f + __expf(-(vir[e] + bir[e] + vhr[e] + bhr[e])));
            float z = 1.f / (1.f + __expf(-(viz[e] + biz[e] + vhz[e] + bhz[e])));
            float n = tanhf(vin[e] + bin[e] + r * (vhn[e] + bhn[e]));
            outv[e] = (1.f - z) * n + z * vh[e];
        }
        *(f32x4*)(ho + jj) = outv;
        xb.x = f2bf(outv[0]); xb.y = f2bf(outv[1]); xb.z = f2bf(outv[2]); xb.w = f2bf(outv[3]);
        *(short4v*)(xp + half * 4) = xb;
    }
}

extern "C" void kernel_launch(void* const* d_in, const int* in_sizes, int n_in,
                              void* d_out, int out_size, void* d_ws, size_t ws_size,
                              hipStream_t stream)
{
    const int*   ids    = (const int*)d_in[0];
    const float* hidden = (const float*)d_in[1];
    const float* emb    = (const float*)d_in[2];
    const float* w_ih   = (const float*)d_in[3];
    const float* w_hh   = (const float*)d_in[4];
    const float* b_ih   = (const float*)d_in[5];
    const float* b_hh   = (const float*)d_in[6];
    const float* dec_w  = (const float*)d_in[7];
    const float* dec_b  = (const float*)d_in[8];

    float* out = (float*)d_out;
    float* logits = out;                                  // [256][50000]
    float* hidden_out = out + (size_t)256 * 50000;        // [2][256][1024]

    short* x_frag = (short*)d_ws;                         // 256*1024 bf16
    short* h_frag = x_frag + 256 * 1024;                  // 2*256*1024 bf16
    float* gi = logits;                                   // scratch in logits region
    float* gh = logits + (size_t)256 * 3072;

    prep_kernel<<<dim3(256, 3), 128, 0, stream>>>(ids, hidden, emb, x_frag, h_frag);

    for (int l = 0; l < 2; ++l) {
        gemm_pipe<1, false><<<192, 256, 0, stream>>>(
            x_frag, w_ih + (size_t)l * 3072 * 1024, gi, 96,
            h_frag + (size_t)l * 256 * 1024, w_hh + (size_t)l * 3072 * 1024, gh,
            nullptr, 3072, 3072);
        gate_kernel<<<256, 128, 0, stream>>>(
            gi, gh, b_ih + (size_t)l * 3072, b_hh + (size_t)l * 3072,
            hidden + (size_t)l * 256 * 1024,
            hidden_out + (size_t)l * 256 * 1024, x_frag);
    }

    // decoder: producer/consumer wave-specialized sequential W streaming
    gemm_dec5<<<782, 512, 0, stream>>>(x_frag, dec_w, logits, dec_b, 50000);
}

// Round 10
// 158.713 us; speedup vs baseline: 1.1593x; 1.1593x over previous
//
#include <hip/hip_runtime.h>

#define KDIM 1024

typedef __attribute__((ext_vector_type(8))) short bf16x8;
typedef __attribute__((ext_vector_type(4))) short short4v;
typedef __attribute__((ext_vector_type(4))) float f32x4;

__device__ __forceinline__ short f2bf(float f) {
    union { float f; unsigned u; } x; x.f = f;
    unsigned r = x.u + 0x7fffu + ((x.u >> 16) & 1u);   // RNE
    return (short)(r >> 16);
}

__device__ __forceinline__ bf16x8 cvt8(f32x4 a, f32x4 b) {
    union { unsigned u[4]; bf16x8 v; } r;
    asm("v_cvt_pk_bf16_f32 %0, %1, %2" : "=v"(r.u[0]) : "v"(a.x), "v"(a.y));
    asm("v_cvt_pk_bf16_f32 %0, %1, %2" : "=v"(r.u[1]) : "v"(a.z), "v"(a.w));
    asm("v_cvt_pk_bf16_f32 %0, %1, %2" : "=v"(r.u[2]) : "v"(b.x), "v"(b.y));
    asm("v_cvt_pk_bf16_f32 %0, %1, %2" : "=v"(r.u[3]) : "v"(b.z), "v"(b.w));
    return r.v;
}

__device__ __forceinline__ void gload16(const void* g, void* l) {
    __builtin_amdgcn_global_load_lds(
        (const __attribute__((address_space(1))) void*)g,
        (__attribute__((address_space(3))) void*)l, 16, 0, 0);
}

#define WAIT_VM(n)  asm volatile("s_waitcnt vmcnt(" #n ")" ::: "memory")
#define BARRIER() do { asm volatile("" ::: "memory"); \
                       __builtin_amdgcn_s_barrier();  \
                       asm volatile("" ::: "memory"); } while (0)

// ---------------------------------------------------------------------------
// Transcode: fp32 W[N][1024] -> bf16 fragment-panel layout in d_ws.
// Panel p = 256 rows (512 KB bf16). Element (n,k):
//   p=n>>8, nr=n&255, nf16=nr>>4, r=nr&15, kf=k>>5, kc=(k>>3)&3, e=k&7
//   short-offset = p*262144 + ((nf16*32+kf)*64 + kc*16 + r)*8 + e
// Thread = one (n, kf) block: reads 128 B contiguous fp32, writes 4x16B.
// Chip-wide the reads are MONOTONE SEQUENTIAL (the m13 6.3 TB/s pattern):
// wave = 8 KB contiguous, consecutive blocks walk consecutive addresses.
// ---------------------------------------------------------------------------
__global__ void transcode_w(const float* __restrict__ W, short* __restrict__ out)
{
    const int gid = blockIdx.x * 256 + threadIdx.x;
    const int n = gid >> 5, kf = gid & 31;
    const float* src = W + (size_t)n * KDIM + kf * 32;
    const int p = n >> 8, nr = n & 255, nf16 = nr >> 4, r = nr & 15;
    short* dst = out + (size_t)p * 262144 + ((size_t)(nf16 * 32 + kf) * 64 + r) * 8;
    #pragma unroll
    for (int kc = 0; kc < 4; ++kc) {
        f32x4 a = *(const f32x4*)(src + kc * 8);
        f32x4 b = *(const f32x4*)(src + kc * 8 + 4);
        *(bf16x8*)(dst + kc * 128) = cvt8(a, b);
    }
}

// ---------------------------------------------------------------------------
// Decoder GEMM v6: C[m][n] = sum_k A[m][k]*Wbf[n][k] + bias[n].
// M=256, K=1024, BN=256, 196 blocks x 512 thr (8 waves: 2M x 4N), acc[8][4].
// W is bf16 in fragment-panel layout (L3-resident, just transcoded):
//   stage(s) = 2 gload16/wave of 1 KB PERFECTLY LINEAR, LDS linear,
//   B-frag ds_read identical to the (proven) A-frag pattern: conflict-free,
//   NO cvt in the hot loop. A staged the same way (R4-proven).
// Ring-3 (96 KB LDS), counted vmcnt 8/4/0 (4 loads/wave/stage), 2 barriers.
// ---------------------------------------------------------------------------
__launch_bounds__(512, 1)
__global__ void gemm_dec6(const short* __restrict__ A, const short* __restrict__ Wb,
                          float* __restrict__ C, const float* __restrict__ bias, int N)
{
    __shared__ __align__(1024) char lds[3][32768];   // [buf][A 16KB | W 16KB]

    const int p = blockIdx.x;
    const int n0 = p * 256;
    const short* Wp = Wb + (size_t)p * 262144;

    const int t = threadIdx.x;
    const int lane = t & 63;
    const int w = t >> 6;       // 0..7
    const int wr = w >> 2;      // m half
    const int wc = w & 3;       // n quarter
    const int cl = lane & 15;

    // staging sources: per wave 2 A chunks + 2 W blocks per step
    const short* gA[2];
    const short* gW[2];
    #pragma unroll
    for (int i = 0; i < 2; ++i) {
        gA[i] = A + (size_t)(w * 2 + i) * 16384 + lane * 8;            // + s*512
        gW[i] = Wp + (size_t)(w * 2 + i) * 16384 + lane * 8;           // + s*512
    }

    f32x4 acc[8][4];
    #pragma unroll
    for (int i = 0; i < 8; ++i)
        #pragma unroll
        for (int j = 0; j < 4; ++j)
            acc[i][j] = (f32x4){0.f, 0.f, 0.f, 0.f};

    auto stage = [&](int s, int buf) {
        char* base = lds[buf];
        #pragma unroll
        for (int i = 0; i < 2; ++i)
            gload16(gW[i] + s * 512, base + 16384 + (w * 2 + i) * 1024);
        #pragma unroll
        for (int i = 0; i < 2; ++i)
            gload16(gA[i] + s * 512, base + (w * 2 + i) * 1024);
    };

    auto compute = [&](int buf) {
        const char* base = lds[buf];
        bf16x8 bfr[4];
        #pragma unroll
        for (int nf = 0; nf < 4; ++nf)
            bfr[nf] = *(const bf16x8*)(base + 16384 + ((wc * 4 + nf) * 64 + lane) * 16);
        #pragma unroll
        for (int mf = 0; mf < 8; ++mf) {
            bf16x8 a = *(const bf16x8*)(base + (wr * 8 + mf) * 1024 + lane * 16);
            #pragma unroll
            for (int nf = 0; nf < 4; ++nf)
                acc[mf][nf] = __builtin_amdgcn_mfma_f32_16x16x32_bf16(a, bfr[nf], acc[mf][nf], 0, 0, 0);
        }
    };

    stage(0, 0);
    stage(1, 1);

    int bc = 0, bp = 2;
    for (int s = 0; s < 32; ++s) {
        if (s + 2 < 32) {
            stage(s + 2, bp);
            WAIT_VM(8);
        } else if (s + 2 == 32) {
            WAIT_VM(4);
        } else {
            WAIT_VM(0);
        }
        BARRIER();               // stage(s) visible
        compute(bc);
        BARRIER();               // buf bc fully read before re-stage
        bc = (bc == 2) ? 0 : bc + 1;
        bp = (bp == 2) ? 0 : bp + 1;
    }

    // epilogue: col = lane&15, row = (lane>>4)*4 + reg
    #pragma unroll
    for (int mf = 0; mf < 8; ++mf) {
        int row = wr * 128 + mf * 16 + ((lane >> 4) << 2);
        #pragma unroll
        for (int nf = 0; nf < 4; ++nf) {
            int col = n0 + wc * 64 + nf * 16 + cl;
            if (col >= N) continue;
            float bv = bias[col];
            #pragma unroll
            for (int r = 0; r < 4; ++r)
                C[(size_t)(row + r) * N + col] = acc[mf][nf][r] + bv;
        }
    }
}

// ---------------------------------------------------------------------------
// GRU gemm (R3 structure, proven; weights L3-resident).
// ---------------------------------------------------------------------------
template<int NF, bool PRED>
__launch_bounds__(256, 2)
__global__ void gemm_pipe(const short* __restrict__ A0, const float* __restrict__ W0,
                          float* __restrict__ C0, int nb0,
                          const short* __restrict__ A1, const float* __restrict__ W1,
                          float* __restrict__ C1,
                          const float* __restrict__ bias, int N, int ldc)
{
    constexpr int WBYTES = NF * 4096;
    constexpr int BUFB   = 16384 + WBYTES;
    __shared__ __align__(1024) char lds[3 * BUFB];

    const int bx = blockIdx.x;
    const short* A; const float* W; float* C; int n0;
    if (bx < nb0) { A = A0; W = W0; C = C0; n0 = bx * (32 * NF); }
    else          { A = A1; W = W1; C = C1; n0 = (bx - nb0) * (32 * NF); }

    const int t = threadIdx.x;
    const int lane = t & 63;
    const int w = t >> 6;
    const int wr = w >> 1;
    const int wc = w & 1;

    const float* gW[NF];
    #pragma unroll
    for (int i = 0; i < NF; ++i) {
        int sl = (i * 4 + w) * 64 + lane;
        int row = sl >> 3, cc = sl & 7;
        int rowg = n0 + row;
        if (PRED) rowg = (rowg < N) ? rowg : (N - 1);
        gW[i] = W + (size_t)rowg * KDIM + ((cc ^ (row & 7)) << 2);
    }
    const short* gA[4];
    #pragma unroll
    for (int j = 0; j < 4; ++j)
        gA[j] = A + (size_t)(j * 4 + w) * 16384 + lane * 8;

    f32x4 acc[8][NF];
    #pragma unroll
    for (int i = 0; i < 8; ++i)
        #pragma unroll
        for (int j = 0; j < NF; ++j)
            acc[i][j] = (f32x4){0.f, 0.f, 0.f, 0.f};

    auto stage = [&](int s, int buf) {
        char* base = lds + buf * BUFB;
        #pragma unroll
        for (int i = 0; i < NF; ++i)
            gload16(gW[i] + s * 32, base + 16384 + (i * 4 + w) * 1024);
        #pragma unroll
        for (int j = 0; j < 4; ++j)
            gload16(gA[j] + s * 512, base + (j * 4 + w) * 1024);
    };

    auto compute = [&](int buf) {
        const char* base = lds + buf * BUFB;
        const char* Wbp = base + 16384;
        bf16x8 bfr[NF];
        #pragma unroll
        for (int nf = 0; nf < NF; ++nf) {
            int row = (wc * NF + nf) * 16 + (lane & 15);
            int c0 = (lane >> 4) << 1;
            f32x4 lo = *(const f32x4*)(Wbp + row * 128 + ((c0 ^ (row & 7)) << 4));
            f32x4 hi = *(const f32x4*)(Wbp + row * 128 + (((c0 + 1) ^ (row & 7)) << 4));
            bfr[nf] = cvt8(lo, hi);
        }
        #pragma unroll
        for (int mf = 0; mf < 8; ++mf) {
            bf16x8 a = *(const bf16x8*)(base + (wr * 8 + mf) * 1024 + lane * 16);
            #pragma unroll
            for (int nf = 0; nf < NF; ++nf)
                acc[mf][nf] = __builtin_amdgcn_mfma_f32_16x16x32_bf16(a, bfr[nf], acc[mf][nf], 0, 0, 0);
        }
    };

    stage(0, 0);
    stage(1, 1);

    int bc = 0, bp = 2;
    for (int s = 0; s < 32; ++s) {
        if (s + 2 < 32) {
            stage(s + 2, bp);
            if constexpr (NF == 2) WAIT_VM(12); else WAIT_VM(10);
        } else if (s + 2 == 32) {
            if constexpr (NF == 2) WAIT_VM(6); else WAIT_VM(5);
        } else {
            WAIT_VM(0);
        }
        BARRIER();
        compute(bc);
        BARRIER();
        bc = (bc == 2) ? 0 : bc + 1;
        bp = (bp == 2) ? 0 : bp + 1;
    }

    #pragma unroll
    for (int mf = 0; mf < 8; ++mf) {
        int row = wr * 128 + mf * 16 + ((lane >> 4) << 2);
        #pragma unroll
        for (int nf = 0; nf < NF; ++nf) {
            int col = n0 + (wc * NF + nf) * 16 + (lane & 15);
            if (PRED && col >= N) continue;
            float bvv = bias ? bias[col] : 0.0f;
            #pragma unroll
            for (int r = 0; r < 4; ++r)
                C[(size_t)(row + r) * ldc + col] = acc[mf][nf][r] + bvv;
        }
    }
}

// Gather embedding row / convert hidden rows into bf16 fragment layout.
__global__ void prep_kernel(const int* __restrict__ ids, const float* __restrict__ hidden,
                            const float* __restrict__ emb,
                            short* __restrict__ x_frag, short* __restrict__ h_frag)
{
    const int m = blockIdx.x;
    const int which = blockIdx.y;
    const int j = threadIdx.x << 3;

    const float* src;
    short* dst;
    if (which == 0) { src = emb + (size_t)ids[m] * KDIM; dst = x_frag; }
    else {
        src = hidden + ((size_t)(which - 1) * 256 + m) * KDIM;
        dst = h_frag + (size_t)(which - 1) * 256 * KDIM;
    }
    f32x4 v0 = *(const f32x4*)(src + j);
    f32x4 v1 = *(const f32x4*)(src + j + 4);
    int mf = m >> 4, rr = m & 15, kf = j >> 5, g = (j >> 3) & 3;
    short* pp = dst + (size_t)((mf * 32 + kf) * 64 + g * 16 + rr) * 8;
    short4v a, b;
    a.x = f2bf(v0.x); a.y = f2bf(v0.y); a.z = f2bf(v0.z); a.w = f2bf(v0.w);
    b.x = f2bf(v1.x); b.y = f2bf(v1.y); b.z = f2bf(v1.z); b.w = f2bf(v1.w);
    *(short4v*)pp = a;
    *(short4v*)(pp + 4) = b;
}

// GRU gates: h_new = (1-z)*n + z*h ; writes fp32 hidden_out and bf16 x fragments.
__global__ void gate_kernel(const float* __restrict__ gi, const float* __restrict__ gh,
                            const float* __restrict__ bi, const float* __restrict__ bh,
                            const float* __restrict__ hprev, float* __restrict__ hout,
                            short* __restrict__ x_frag)
{
    const int m = blockIdx.x;
    const int j = threadIdx.x << 3;
    const float* gim = gi + (size_t)m * 3072;
    const float* ghm = gh + (size_t)m * 3072;
    const float* hp = hprev + (size_t)m * KDIM;
    float* ho = hout + (size_t)m * KDIM;
    int mf = m >> 4, rr = m & 15, kf = j >> 5, g = (j >> 3) & 3;
    short* xp = x_frag + (size_t)((mf * 32 + kf) * 64 + g * 16 + rr) * 8;

    #pragma unroll
    for (int half = 0; half < 2; ++half) {
        int jj = j + half * 4;
        f32x4 vir = *(const f32x4*)(gim + jj);
        f32x4 viz = *(const f32x4*)(gim + 1024 + jj);
        f32x4 vin = *(const f32x4*)(gim + 2048 + jj);
        f32x4 vhr = *(const f32x4*)(ghm + jj);
        f32x4 vhz = *(const f32x4*)(ghm + 1024 + jj);
        f32x4 vhn = *(const f32x4*)(ghm + 2048 + jj);
        f32x4 bir = *(const f32x4*)(bi + jj);
        f32x4 biz = *(const f32x4*)(bi + 1024 + jj);
        f32x4 bin = *(const f32x4*)(bi + 2048 + jj);
        f32x4 bhr = *(const f32x4*)(bh + jj);
        f32x4 bhz = *(const f32x4*)(bh + 1024 + jj);
        f32x4 bhn = *(const f32x4*)(bh + 2048 + jj);
        f32x4 vh  = *(const f32x4*)(hp + jj);
        f32x4 outv;
        short4v xb;
        #pragma unroll
        for (int e = 0; e < 4; ++e) {
            float r = 1.f / (1.f + __expf(-(vir[e] + bir[e] + vhr[e] + bhr[e])));
            float z = 1.f / (1.f + __expf(-(viz[e] + biz[e] + vhz[e] + bhz[e])));
            float n = tanhf(vin[e] + bin[e] + r * (vhn[e] + bhn[e]));
            outv[e] = (1.f - z) * n + z * vh[e];
        }
        *(f32x4*)(ho + jj) = outv;
        xb.x = f2bf(outv[0]); xb.y = f2bf(outv[1]); xb.z = f2bf(outv[2]); xb.w = f2bf(outv[3]);
        *(short4v*)(xp + half * 4) = xb;
    }
}

extern "C" void kernel_launch(void* const* d_in, const int* in_sizes, int n_in,
                              void* d_out, int out_size, void* d_ws, size_t ws_size,
                              hipStream_t stream)
{
    const int*   ids    = (const int*)d_in[0];
    const float* hidden = (const float*)d_in[1];
    const float* emb    = (const float*)d_in[2];
    const float* w_ih   = (const float*)d_in[3];
    const float* w_hh   = (const float*)d_in[4];
    const float* b_ih   = (const float*)d_in[5];
    const float* b_hh   = (const float*)d_in[6];
    const float* dec_w  = (const float*)d_in[7];
    const float* dec_b  = (const float*)d_in[8];

    float* out = (float*)d_out;
    float* logits = out;                                  // [256][50000]
    float* hidden_out = out + (size_t)256 * 50000;        // [2][256][1024]

    short* x_frag = (short*)d_ws;                         // 512 KB
    short* h_frag = x_frag + 256 * 1024;                  // 1 MB
    short* w_bf   = (short*)((char*)d_ws + (size_t)16 * 1024 * 1024);  // ~100.4 MB
    float* gi = logits;                                   // scratch in logits region
    float* gh = logits + (size_t)256 * 3072;

    prep_kernel<<<dim3(256, 3), 128, 0, stream>>>(ids, hidden, emb, x_frag, h_frag);

    // decode-weight transcode: monotone sequential read (m13 pattern)
    transcode_w<<<6250, 256, 0, stream>>>(dec_w, w_bf);

    for (int l = 0; l < 2; ++l) {
        gemm_pipe<1, false><<<192, 256, 0, stream>>>(
            x_frag, w_ih + (size_t)l * 3072 * 1024, gi, 96,
            h_frag + (size_t)l * 256 * 1024, w_hh + (size_t)l * 3072 * 1024, gh,
            nullptr, 3072, 3072);
        gate_kernel<<<256, 128, 0, stream>>>(
            gi, gh, b_ih + (size_t)l * 3072, b_hh + (size_t)l * 3072,
            hidden + (size_t)l * 256 * 1024,
            hidden_out + (size_t)l * 256 * 1024, x_frag);
    }

    // decoder: bf16 fragment-panel W (L3-resident), linear DMA staging
    gemm_dec6<<<196, 512, 0, stream>>>(x_frag, w_bf, logits, dec_b, 50000);
}

// Round 11
// 147.069 us; speedup vs baseline: 1.2511x; 1.0792x over previous
//
#include <hip/hip_runtime.h>

#define KDIM 1024

typedef __attribute__((ext_vector_type(8))) short bf16x8;
typedef __attribute__((ext_vector_type(4))) short short4v;
typedef __attribute__((ext_vector_type(4))) float f32x4;

__device__ __forceinline__ short f2bf(float f) {
    union { float f; unsigned u; } x; x.f = f;
    unsigned r = x.u + 0x7fffu + ((x.u >> 16) & 1u);   // RNE
    return (short)(r >> 16);
}

__device__ __forceinline__ bf16x8 cvt8(f32x4 a, f32x4 b) {
    union { unsigned u[4]; bf16x8 v; } r;
    asm("v_cvt_pk_bf16_f32 %0, %1, %2" : "=v"(r.u[0]) : "v"(a.x), "v"(a.y));
    asm("v_cvt_pk_bf16_f32 %0, %1, %2" : "=v"(r.u[1]) : "v"(a.z), "v"(a.w));
    asm("v_cvt_pk_bf16_f32 %0, %1, %2" : "=v"(r.u[2]) : "v"(b.x), "v"(b.y));
    asm("v_cvt_pk_bf16_f32 %0, %1, %2" : "=v"(r.u[3]) : "v"(b.z), "v"(b.w));
    return r.v;
}

__device__ __forceinline__ void gload16(const void* g, void* l) {
    __builtin_amdgcn_global_load_lds(
        (const __attribute__((address_space(1))) void*)g,
        (__attribute__((address_space(3))) void*)l, 16, 0, 0);
}

#define WAIT_VM(n)  asm volatile("s_waitcnt vmcnt(" #n ")" ::: "memory")
#define BARRIER() do { asm volatile("" ::: "memory"); \
                       __builtin_amdgcn_s_barrier();  \
                       asm volatile("" ::: "memory"); } while (0)

// ---------------------------------------------------------------------------
// Transcode v2: fp32 W[N][1024] -> bf16 fragment-panel layout, LINEAR on
// both global sides (the m13 6.3 TB/s pattern). Block = 16 consecutive rows:
//   read 64 KB contiguous fp32 (lane = 32 B), cvt -> bf16,
//   scatter into LDS in fragment order (bank-swizzled, involution
//   addr ^= ((addr>>8)&7)<<4), barrier,
//   write 32 KB contiguous bf16 (lane = 16 B).
// Output granule (kf,g,r) of block b lands at out + b*16384 + (kf*64+g*16+r)*8
// -- block output is one contiguous 32 KB run. 3125 blocks x 256 thr.
// ---------------------------------------------------------------------------
__global__ void transcode_w2(const float* __restrict__ W, short* __restrict__ out)
{
    __shared__ short sbuf[16384];            // 32 KB
    const int b = blockIdx.x;
    const int t = threadIdx.x;

    const float* src = W + (size_t)b * 16384;
    #pragma unroll
    for (int j = 0; j < 8; ++j) {
        int g8 = j * 256 + t;                // bf16x8 granule index, 0..2047
        f32x4 a  = *(const f32x4*)(src + (size_t)g8 * 8);
        f32x4 bb = *(const f32x4*)(src + (size_t)g8 * 8 + 4);
        int r = g8 >> 7, k8 = g8 & 127;
        int kf = k8 >> 2, g = k8 & 3;
        int baddr = ((kf * 64 + g * 16 + r) * 8) * 2;     // bytes
        baddr ^= ((baddr >> 8) & 7) << 4;                 // bank swizzle
        *(bf16x8*)((char*)sbuf + baddr) = cvt8(a, bb);
    }
    __syncthreads();
    short* dst = out + (size_t)b * 16384;
    #pragma unroll
    for (int j = 0; j < 8; ++j) {
        int o = j * 256 + t;
        int baddr = o * 16;
        baddr ^= ((baddr >> 8) & 7) << 4;                 // same involution
        *(bf16x8*)(dst + (size_t)o * 8) = *(const bf16x8*)((char*)sbuf + baddr);
    }
}

// ---------------------------------------------------------------------------
// Decoder GEMM v6 (UNCHANGED from R10): bf16 fragment-panel W, linear DMA
// staging, ring-3, counted vmcnt 8/4/0, 2 barriers, 196 blocks x 512 thr.
// ---------------------------------------------------------------------------
__launch_bounds__(512, 1)
__global__ void gemm_dec6(const short* __restrict__ A, const short* __restrict__ Wb,
                          float* __restrict__ C, const float* __restrict__ bias, int N)
{
    __shared__ __align__(1024) char lds[3][32768];   // [buf][A 16KB | W 16KB]

    const int p = blockIdx.x;
    const int n0 = p * 256;
    const short* Wp = Wb + (size_t)p * 262144;

    const int t = threadIdx.x;
    const int lane = t & 63;
    const int w = t >> 6;
    const int wr = w >> 2;
    const int wc = w & 3;
    const int cl = lane & 15;

    const short* gA[2];
    const short* gW[2];
    #pragma unroll
    for (int i = 0; i < 2; ++i) {
        gA[i] = A + (size_t)(w * 2 + i) * 16384 + lane * 8;
        gW[i] = Wp + (size_t)(w * 2 + i) * 16384 + lane * 8;
    }

    f32x4 acc[8][4];
    #pragma unroll
    for (int i = 0; i < 8; ++i)
        #pragma unroll
        for (int j = 0; j < 4; ++j)
            acc[i][j] = (f32x4){0.f, 0.f, 0.f, 0.f};

    auto stage = [&](int s, int buf) {
        char* base = lds[buf];
        #pragma unroll
        for (int i = 0; i < 2; ++i)
            gload16(gW[i] + s * 512, base + 16384 + (w * 2 + i) * 1024);
        #pragma unroll
        for (int i = 0; i < 2; ++i)
            gload16(gA[i] + s * 512, base + (w * 2 + i) * 1024);
    };

    auto compute = [&](int buf) {
        const char* base = lds[buf];
        bf16x8 bfr[4];
        #pragma unroll
        for (int nf = 0; nf < 4; ++nf)
            bfr[nf] = *(const bf16x8*)(base + 16384 + ((wc * 4 + nf) * 64 + lane) * 16);
        #pragma unroll
        for (int mf = 0; mf < 8; ++mf) {
            bf16x8 a = *(const bf16x8*)(base + (wr * 8 + mf) * 1024 + lane * 16);
            #pragma unroll
            for (int nf = 0; nf < 4; ++nf)
                acc[mf][nf] = __builtin_amdgcn_mfma_f32_16x16x32_bf16(a, bfr[nf], acc[mf][nf], 0, 0, 0);
        }
    };

    stage(0, 0);
    stage(1, 1);

    int bc = 0, bp = 2;
    for (int s = 0; s < 32; ++s) {
        if (s + 2 < 32) {
            stage(s + 2, bp);
            WAIT_VM(8);
        } else if (s + 2 == 32) {
            WAIT_VM(4);
        } else {
            WAIT_VM(0);
        }
        BARRIER();
        compute(bc);
        BARRIER();
        bc = (bc == 2) ? 0 : bc + 1;
        bp = (bp == 2) ? 0 : bp + 1;
    }

    #pragma unroll
    for (int mf = 0; mf < 8; ++mf) {
        int row = wr * 128 + mf * 16 + ((lane >> 4) << 2);
        #pragma unroll
        for (int nf = 0; nf < 4; ++nf) {
            int col = n0 + wc * 64 + nf * 16 + cl;
            if (col >= N) continue;
            float bv = bias[col];
            #pragma unroll
            for (int r = 0; r < 4; ++r)
                C[(size_t)(row + r) * N + col] = acc[mf][nf][r] + bv;
        }
    }
}

// ---------------------------------------------------------------------------
// GRU gemm (R3 structure, proven; weights L3-resident).
// ---------------------------------------------------------------------------
template<int NF, bool PRED>
__launch_bounds__(256, 2)
__global__ void gemm_pipe(const short* __restrict__ A0, const float* __restrict__ W0,
                          float* __restrict__ C0, int nb0,
                          const short* __restrict__ A1, const float* __restrict__ W1,
                          float* __restrict__ C1,
                          const float* __restrict__ bias, int N, int ldc)
{
    constexpr int WBYTES = NF * 4096;
    constexpr int BUFB   = 16384 + WBYTES;
    __shared__ __align__(1024) char lds[3 * BUFB];

    const int bx = blockIdx.x;
    const short* A; const float* W; float* C; int n0;
    if (bx < nb0) { A = A0; W = W0; C = C0; n0 = bx * (32 * NF); }
    else          { A = A1; W = W1; C = C1; n0 = (bx - nb0) * (32 * NF); }

    const int t = threadIdx.x;
    const int lane = t & 63;
    const int w = t >> 6;
    const int wr = w >> 1;
    const int wc = w & 1;

    const float* gW[NF];
    #pragma unroll
    for (int i = 0; i < NF; ++i) {
        int sl = (i * 4 + w) * 64 + lane;
        int row = sl >> 3, cc = sl & 7;
        int rowg = n0 + row;
        if (PRED) rowg = (rowg < N) ? rowg : (N - 1);
        gW[i] = W + (size_t)rowg * KDIM + ((cc ^ (row & 7)) << 2);
    }
    const short* gA[4];
    #pragma unroll
    for (int j = 0; j < 4; ++j)
        gA[j] = A + (size_t)(j * 4 + w) * 16384 + lane * 8;

    f32x4 acc[8][NF];
    #pragma unroll
    for (int i = 0; i < 8; ++i)
        #pragma unroll
        for (int j = 0; j < NF; ++j)
            acc[i][j] = (f32x4){0.f, 0.f, 0.f, 0.f};

    auto stage = [&](int s, int buf) {
        char* base = lds + buf * BUFB;
        #pragma unroll
        for (int i = 0; i < NF; ++i)
            gload16(gW[i] + s * 32, base + 16384 + (i * 4 + w) * 1024);
        #pragma unroll
        for (int j = 0; j < 4; ++j)
            gload16(gA[j] + s * 512, base + (j * 4 + w) * 1024);
    };

    auto compute = [&](int buf) {
        const char* base = lds + buf * BUFB;
        const char* Wbp = base + 16384;
        bf16x8 bfr[NF];
        #pragma unroll
        for (int nf = 0; nf < NF; ++nf) {
            int row = (wc * NF + nf) * 16 + (lane & 15);
            int c0 = (lane >> 4) << 1;
            f32x4 lo = *(const f32x4*)(Wbp + row * 128 + ((c0 ^ (row & 7)) << 4));
            f32x4 hi = *(const f32x4*)(Wbp + row * 128 + (((c0 + 1) ^ (row & 7)) << 4));
            bfr[nf] = cvt8(lo, hi);
        }
        #pragma unroll
        for (int mf = 0; mf < 8; ++mf) {
            bf16x8 a = *(const bf16x8*)(base + (wr * 8 + mf) * 1024 + lane * 16);
            #pragma unroll
            for (int nf = 0; nf < NF; ++nf)
                acc[mf][nf] = __builtin_amdgcn_mfma_f32_16x16x32_bf16(a, bfr[nf], acc[mf][nf], 0, 0, 0);
        }
    };

    stage(0, 0);
    stage(1, 1);

    int bc = 0, bp = 2;
    for (int s = 0; s < 32; ++s) {
        if (s + 2 < 32) {
            stage(s + 2, bp);
            if constexpr (NF == 2) WAIT_VM(12); else WAIT_VM(10);
        } else if (s + 2 == 32) {
            if constexpr (NF == 2) WAIT_VM(6); else WAIT_VM(5);
        } else {
            WAIT_VM(0);
        }
        BARRIER();
        compute(bc);
        BARRIER();
        bc = (bc == 2) ? 0 : bc + 1;
        bp = (bp == 2) ? 0 : bp + 1;
    }

    #pragma unroll
    for (int mf = 0; mf < 8; ++mf) {
        int row = wr * 128 + mf * 16 + ((lane >> 4) << 2);
        #pragma unroll
        for (int nf = 0; nf < NF; ++nf) {
            int col = n0 + (wc * NF + nf) * 16 + (lane & 15);
            if (PRED && col >= N) continue;
            float bvv = bias ? bias[col] : 0.0f;
            #pragma unroll
            for (int r = 0; r < 4; ++r)
                C[(size_t)(row + r) * ldc + col] = acc[mf][nf][r] + bvv;
        }
    }
}

// Gather embedding row / convert hidden rows into bf16 fragment layout.
__global__ void prep_kernel(const int* __restrict__ ids, const float* __restrict__ hidden,
                            const float* __restrict__ emb,
                            short* __restrict__ x_frag, short* __restrict__ h_frag)
{
    const int m = blockIdx.x;
    const int which = blockIdx.y;
    const int j = threadIdx.x << 3;

    const float* src;
    short* dst;
    if (which == 0) { src = emb + (size_t)ids[m] * KDIM; dst = x_frag; }
    else {
        src = hidden + ((size_t)(which - 1) * 256 + m) * KDIM;
        dst = h_frag + (size_t)(which - 1) * 256 * KDIM;
    }
    f32x4 v0 = *(const f32x4*)(src + j);
    f32x4 v1 = *(const f32x4*)(src + j + 4);
    int mf = m >> 4, rr = m & 15, kf = j >> 5, g = (j >> 3) & 3;
    short* pp = dst + (size_t)((mf * 32 + kf) * 64 + g * 16 + rr) * 8;
    short4v a, b;
    a.x = f2bf(v0.x); a.y = f2bf(v0.y); a.z = f2bf(v0.z); a.w = f2bf(v0.w);
    b.x = f2bf(v1.x); b.y = f2bf(v1.y); b.z = f2bf(v1.z); b.w = f2bf(v1.w);
    *(short4v*)pp = a;
    *(short4v*)(pp + 4) = b;
}

// GRU gates: h_new = (1-z)*n + z*h ; writes fp32 hidden_out and bf16 x fragments.
__global__ void gate_kernel(const float* __restrict__ gi, const float* __restrict__ gh,
                            const float* __restrict__ bi, const float* __restrict__ bh,
                            const float* __restrict__ hprev, float* __restrict__ hout,
                            short* __restrict__ x_frag)
{
    const int m = blockIdx.x;
    const int j = threadIdx.x << 3;
    const float* gim = gi + (size_t)m * 3072;
    const float* ghm = gh + (size_t)m * 3072;
    const float* hp = hprev + (size_t)m * KDIM;
    float* ho = hout + (size_t)m * KDIM;
    int mf = m >> 4, rr = m & 15, kf = j >> 5, g = (j >> 3) & 3;
    short* xp = x_frag + (size_t)((mf * 32 + kf) * 64 + g * 16 + rr) * 8;

    #pragma unroll
    for (int half = 0; half < 2; ++half) {
        int jj = j + half * 4;
        f32x4 vir = *(const f32x4*)(gim + jj);
        f32x4 viz = *(const f32x4*)(gim + 1024 + jj);
        f32x4 vin = *(const f32x4*)(gim + 2048 + jj);
        f32x4 vhr = *(const f32x4*)(ghm + jj);
        f32x4 vhz = *(const f32x4*)(ghm + 1024 + jj);
        f32x4 vhn = *(const f32x4*)(ghm + 2048 + jj);
        f32x4 bir = *(const f32x4*)(bi + jj);
        f32x4 biz = *(const f32x4*)(bi + 1024 + jj);
        f32x4 bin = *(const f32x4*)(bi + 2048 + jj);
        f32x4 bhr = *(const f32x4*)(bh + jj);
        f32x4 bhz = *(const f32x4*)(bh + 1024 + jj);
        f32x4 bhn = *(const f32x4*)(bh + 2048 + jj);
        f32x4 vh  = *(const f32x4*)(hp + jj);
        f32x4 outv;
        short4v xb;
        #pragma unroll
        for (int e = 0; e < 4; ++e) {
            float r = 1.f / (1.f + __expf(-(vir[e] + bir[e] + vhr[e] + bhr[e])));
            float z = 1.f / (1.f + __expf(-(viz[e] + biz[e] + vhz[e] + bhz[e])));
            float n = tanhf(vin[e] + bin[e] + r * (vhn[e] + bhn[e]));
            outv[e] = (1.f - z) * n + z * vh[e];
        }
        *(f32x4*)(ho + jj) = outv;
        xb.x = f2bf(outv[0]); xb.y = f2bf(outv[1]); xb.z = f2bf(outv[2]); xb.w = f2bf(outv[3]);
        *(short4v*)(xp + half * 4) = xb;
    }
}

extern "C" void kernel_launch(void* const* d_in, const int* in_sizes, int n_in,
                              void* d_out, int out_size, void* d_ws, size_t ws_size,
                              hipStream_t stream)
{
    const int*   ids    = (const int*)d_in[0];
    const float* hidden = (const float*)d_in[1];
    const float* emb    = (const float*)d_in[2];
    const float* w_ih   = (const float*)d_in[3];
    const float* w_hh   = (const float*)d_in[4];
    const float* b_ih   = (const float*)d_in[5];
    const float* b_hh   = (const float*)d_in[6];
    const float* dec_w  = (const float*)d_in[7];
    const float* dec_b  = (const float*)d_in[8];

    float* out = (float*)d_out;
    float* logits = out;                                  // [256][50000]
    float* hidden_out = out + (size_t)256 * 50000;        // [2][256][1024]

    short* x_frag = (short*)d_ws;                         // 512 KB
    short* h_frag = x_frag + 256 * 1024;                  // 1 MB
    short* w_bf   = (short*)((char*)d_ws + (size_t)16 * 1024 * 1024);  // ~100.4 MB
    float* gi = logits;                                   // scratch in logits region
    float* gh = logits + (size_t)256 * 3072;

    prep_kernel<<<dim3(256, 3), 128, 0, stream>>>(ids, hidden, emb, x_frag, h_frag);

    // decode-weight transcode: linear read AND linear write (m13 pattern both ways)
    transcode_w2<<<3125, 256, 0, stream>>>(dec_w, w_bf);

    for (int l = 0; l < 2; ++l) {
        gemm_pipe<1, false><<<192, 256, 0, stream>>>(
            x_frag, w_ih + (size_t)l * 3072 * 1024, gi, 96,
            h_frag + (size_t)l * 256 * 1024, w_hh + (size_t)l * 3072 * 1024, gh,
            nullptr, 3072, 3072);
        gate_kernel<<<256, 128, 0, stream>>>(
            gi, gh, b_ih + (size_t)l * 3072, b_hh + (size_t)l * 3072,
            hidden + (size_t)l * 256 * 1024,
            hidden_out + (size_t)l * 256 * 1024, x_frag);
    }

    // decoder: bf16 fragment-panel W (L3-resident), linear DMA staging
    gemm_dec6<<<196, 512, 0, stream>>>(x_frag, w_bf, logits, dec_b, 50000);
}